// Round 1
// baseline (481.636 us; speedup 1.0000x reference)
//
#include <hip/hip_runtime.h>
#include <hip/hip_bf16.h>
#include <math.h>

// ---------------------------------------------------------------------------
// HeterogeneousSupervisedTopicModel fwd: recon_loss, other_loss, kld_theta
// B=512, V=50000, K=50, H=300.
// Round 5: k_prep convert phases restructured as grid-stride loops with
// 4-way ILP (2048 long-running blocks instead of 19831 one-shot blocks).
// Counters showed k_prep latency-bound: 2.28 TB/s, VALUBusy 7%, occ 71%.
// Layouts and all downstream kernels unchanged.
//   nbb  [st][512][32] bf16   (nb converted, zero-padded to VP)
//   Wcatb[st][384][32] bf16   (rows 0..299 W1, 320..369 beta*gamma, 370 bow_w)
// ---------------------------------------------------------------------------

#define B_  512
#define V_  50000
#define VP  50016    // V padded to multiple of 32
#define K_  50
#define H_  300
#define KP  64
#define NW  384
#define NSTEP 1563   // VP/32
#define NSB  782     // ceil(V/64)  beta/gamma blocks
#define NB1C 768     // W1-convert grid-stride blocks
#define NB2C 1280    // nb-convert grid-stride blocks

typedef __attribute__((ext_vector_type(8))) short short8;
typedef __attribute__((ext_vector_type(4))) float f32x4;

static __device__ __forceinline__ short bf16s(float f) {
  unsigned int u = __builtin_bit_cast(unsigned int, f);
  u += 0x7fffu + ((u >> 16) & 1u);
  return (short)(u >> 16);
}

static __device__ __forceinline__ unsigned int pkbf(float lo, float hi) {
  __hip_bfloat162 t = __float22bfloat162_rn(float2{lo, hi});
  unsigned int u; __builtin_memcpy(&u, &t, 4); return u;
}

static __device__ __forceinline__ short8 to_bf8(float4 a, float4 b) {
  unsigned int u[4];
  u[0] = pkbf(a.x, a.y); u[1] = pkbf(a.z, a.w);
  u[2] = pkbf(b.x, b.y); u[3] = pkbf(b.z, b.w);
  short8 r; __builtin_memcpy(&r, u, 16); return r;
}

// ---------------------------------------------------------------------------
// k_prep, three block ranges in one launch:
//  [0, NB1C)             : Wcatb rows 0..299 = bf16(W1), K-tile-major
//                          (grid-stride, 4-way unrolled ILP)
//  [NB1C, NB1C+NSB)      : per 64-v tile: Wcatb rows 300..383 (320..369 =
//                          (beta*gamma)^T, 370 = bow_w, rest 0); betab[V][64];
//                          partials pg/pbr/pbw2
//  [NB1C+NSB, +NB2C)     : nbb = bf16(nb), K-tile-major, zero-padded
//                          (grid-stride, 4-way unrolled ILP)
// ---------------------------------------------------------------------------
__global__ __launch_bounds__(256) void k_prep(
    const float* __restrict__ W1,
    const float* __restrict__ beta, const float* __restrict__ gamma,
    const float* __restrict__ br,   const float* __restrict__ bw,
    const float* __restrict__ nb,
    short* __restrict__ Wcatb, short* __restrict__ betab,
    short* __restrict__ nbb,
    float* __restrict__ pg, float* __restrict__ pbr, float* __restrict__ pbw2)
{
  __shared__ short sbt[64 * 52];
  __shared__ short bbt[64 * 52];
  __shared__ float redA[4];
  const int tid = threadIdx.x;
  const short8 z8 = {0, 0, 0, 0, 0, 0, 0, 0};

  if (blockIdx.x < NB1C) {
    // ---- W1 convert: grid-stride over (st, n, kq) units, 4-way ILP ----
    const int NU = NSTEP * 1200;         // 1,875,600 units (one short8 each)
    const int stride = NB1C * 256;
    int idx = blockIdx.x * 256 + tid;
    for (; idx + 3 * stride < NU; idx += 4 * stride) {
      float4 a[4], b[4];
      short* dst[4];
      bool ok[4];
      #pragma unroll
      for (int u = 0; u < 4; ++u) {
        const int id = idx + u * stride;
        const int st = id / 1200;
        const int rem = id - st * 1200;
        const int n = rem >> 2, kq = rem & 3;
        const int kb = st * 32 + kq * 8;
        ok[u] = (kb + 8 <= V_);
        dst[u] = Wcatb + (size_t)st * 12288 + n * 32 + kq * 8;
        if (ok[u]) {
          const float4* p = (const float4*)(W1 + (size_t)n * V_ + kb);
          a[u] = p[0]; b[u] = p[1];
        }
      }
      #pragma unroll
      for (int u = 0; u < 4; ++u) {
        short8 o = ok[u] ? to_bf8(a[u], b[u]) : z8;
        *(short8*)dst[u] = o;
      }
    }
    for (; idx < NU; idx += stride) {
      const int st = idx / 1200;
      const int rem = idx - st * 1200;
      const int n = rem >> 2, kq = rem & 3;
      const int kb = st * 32 + kq * 8;
      short8 o = z8;
      if (kb + 8 <= V_) {
        const float4* p = (const float4*)(W1 + (size_t)n * V_ + kb);
        o = to_bf8(p[0], p[1]);
      }
      *(short8*)(Wcatb + (size_t)st * 12288 + n * 32 + kq * 8) = o;
    }
    return;
  }

  if (blockIdx.x >= NB1C + NSB) {
    // ---- nb convert: grid-stride over (st, r, kq) units, 4-way ILP ----
    const int NU = NSTEP * 2048;         // 3,201,024 units
    const int stride = NB2C * 256;
    int idx = (blockIdx.x - (NB1C + NSB)) * 256 + tid;
    for (; idx + 3 * stride < NU; idx += 4 * stride) {
      float4 a[4], b[4];
      short* dst[4];
      bool ok[4];
      #pragma unroll
      for (int u = 0; u < 4; ++u) {
        const int id = idx + u * stride;
        const int st = id >> 11;
        const int r  = (id >> 2) & 511;
        const int kq = id & 3;
        const int kb = st * 32 + kq * 8;
        ok[u] = (kb + 8 <= V_);
        dst[u] = nbb + (size_t)st * 16384 + r * 32 + kq * 8;
        if (ok[u]) {
          const float4* p = (const float4*)(nb + (size_t)r * V_ + kb);
          a[u] = p[0]; b[u] = p[1];
        }
      }
      #pragma unroll
      for (int u = 0; u < 4; ++u) {
        short8 o = ok[u] ? to_bf8(a[u], b[u]) : z8;
        *(short8*)dst[u] = o;
      }
    }
    for (; idx < NU; idx += stride) {
      const int st = idx >> 11;
      const int r  = (idx >> 2) & 511;
      const int kq = idx & 3;
      const int kb = st * 32 + kq * 8;
      short8 o = z8;
      if (kb + 8 <= V_) {
        const float4* p = (const float4*)(nb + (size_t)r * V_ + kb);
        o = to_bf8(p[0], p[1]);
      }
      *(short8*)(nbb + (size_t)st * 16384 + r * 32 + kq * 8) = o;
    }
    return;
  }

  // ---- beta/gamma tile ----
  const int blk = blockIdx.x - NB1C;                 // 0..781
  const int v0 = blk * 64;
  const int nvalid = (V_ - v0 < 64) ? (V_ - v0) : 64;
  const int nwrite = (VP - v0 < 64) ? (VP - v0) : 64;

  const int nf4 = (nvalid * 50) / 4;
  const float4* bsrc = (const float4*)(beta  + (size_t)v0 * 50);
  const float4* gsrc = (const float4*)(gamma + (size_t)v0 * 50);
  float gabs = 0.f;
  for (int f = tid; f < nf4; f += 256) {
    float4 bv = bsrc[f];
    float4 gv = gsrc[f];
    float be[4] = {bv.x, bv.y, bv.z, bv.w};
    float ge[4] = {gv.x, gv.y, gv.z, gv.w};
    #pragma unroll
    for (int e = 0; e < 4; ++e) {
      int idx = f * 4 + e;
      int j = idx / 50, k = idx - j * 50;
      gabs += fabsf(ge[e]);
      bbt[j * 52 + k] = bf16s(be[e]);
      sbt[j * 52 + k] = bf16s(be[e] * ge[e]);
    }
  }
  #pragma unroll
  for (int off = 1; off < 64; off <<= 1) gabs += __shfl_xor(gabs, off, 64);
  if ((tid & 63) == 0) redA[tid >> 6] = gabs;
  if (tid < 64) {
    float s1 = 0.f, s2 = 0.f;
    if (tid < nvalid) {
      s1 = fabsf(br[v0 + tid]);
      float w = bw[v0 + tid]; s2 = w * w;
    }
    #pragma unroll
    for (int off = 1; off < 64; off <<= 1) {
      s1 += __shfl_xor(s1, off, 64);
      s2 += __shfl_xor(s2, off, 64);
    }
    if (tid == 0) { pbr[blk] = s1; pbw2[blk] = s2; }
  }
  __syncthreads();
  if (tid == 0) pg[blk] = redA[0] + redA[1] + redA[2] + redA[3];

  const int j = tid & 63;
  const int q = tid >> 6;
  // Wcatb rows 300..383, this tile's 2 st-chunks (st = blk*2 + j/32)
  #pragma unroll
  for (int p = 0; p < 21; ++p) {
    const int kk = p * 4 + q;          // 0..83
    if (j < nwrite) {
      short val = 0;
      if (j < nvalid) {
        if (kk >= 20 && kk < 70)      val = sbt[j * 52 + (kk - 20)];
        else if (kk == 70)            val = bf16s(bw[v0 + j]);
      }
      Wcatb[(size_t)(blk * 2 + (j >> 5)) * 12288 + (300 + kk) * 32 + (j & 31)] = val;
    }
  }
  // betab rows
  if (j < nvalid) {
    __attribute__((aligned(16))) short tmp[16];
    #pragma unroll
    for (int t = 0; t < 16; ++t) {
      int k = q * 16 + t;
      tmp[t] = (k < K_) ? bbt[j * 52 + k] : (short)0;
    }
    short8* dst = (short8*)(betab + (size_t)(v0 + j) * 64 + q * 16);
    dst[0] = *(const short8*)&tmp[0];
    dst[1] = *(const short8*)&tmp[8];
  }
}

// ---------------------------------------------------------------------------
// k_bg: part[s][512][384] = slab-partial of nbb @ Wcatb^T (both bf16,
// K-tile-major).  Inner loop: 8 contiguous 16B loads + 16 MFMA, no cvt.
// Register double-buffer.  grid = 12 * S, 3 blocks/CU.
// ---------------------------------------------------------------------------
__global__ __launch_bounds__(256, 3) void k_bg(
    const short* __restrict__ Ab, const short* __restrict__ Bb,
    float* __restrict__ part, int sps)
{
  const int t = blockIdx.x;
  const int s = t / 12;
  const int r = t % 12;
  const int bni = r % 3, bmi = r / 3;
  const int lane = threadIdx.x & 63, wv = threadIdx.x >> 6;
  const int l15 = lane & 15, quad = lane >> 4;
  const int m0 = bmi * 128 + (wv & 1) * 64;
  const int n0 = bni * 128 + (wv >> 1) * 64;
  int st0 = s * sps, st1 = st0 + sps;
  if (st0 > NSTEP) st0 = NSTEP;
  if (st1 > NSTEP) st1 = NSTEP;
  const int nst = st1 - st0;

  const short8* pa = (const short8*)Ab + (size_t)st0 * 2048 + (m0 + l15) * 4 + quad;
  const short8* pb = (const short8*)Bb + (size_t)st0 * 1536 + (n0 + l15) * 4 + quad;

  f32x4 acc[4][4];
  #pragma unroll
  for (int i = 0; i < 4; ++i)
    #pragma unroll
    for (int jj = 0; jj < 4; ++jj) acc[i][jj] = f32x4{0.f, 0.f, 0.f, 0.f};

  short8 A0[4], A1[4], B0[4], B1[4];

  auto ld = [&](short8 (&Af)[4], short8 (&Bf)[4]) {
    #pragma unroll
    for (int i = 0; i < 4; ++i) Af[i] = pa[i * 64];
    #pragma unroll
    for (int jj = 0; jj < 4; ++jj) Bf[jj] = pb[jj * 64];
    pa += 2048; pb += 1536;
  };
  auto comp = [&](short8 (&Af)[4], short8 (&Bf)[4]) {
    #pragma unroll
    for (int i = 0; i < 4; ++i)
      #pragma unroll
      for (int jj = 0; jj < 4; ++jj)
        acc[i][jj] = __builtin_amdgcn_mfma_f32_16x16x32_bf16(Af[i], Bf[jj], acc[i][jj], 0, 0, 0);
  };

  if (nst > 0) {
    ld(A0, B0);
    int k = 0;
    for (; k + 2 <= nst; k += 2) {
      ld(A1, B1);                      // step k+1 (valid: k+1 < nst)
      comp(A0, B0);                    // step k
      if (k + 2 < nst) ld(A0, B0);     // step k+2
      comp(A1, B1);                    // step k+1
    }
    if (k < nst) comp(A0, B0);         // odd tail
  }

  float* op = part + (size_t)s * (B_ * NW);
  #pragma unroll
  for (int i = 0; i < 4; ++i)
    #pragma unroll
    for (int jj = 0; jj < 4; ++jj)
      #pragma unroll
      for (int rr = 0; rr < 4; ++rr)
        op[(size_t)(m0 + 16 * i + quad * 4 + rr) * NW + (n0 + 16 * jj + l15)] = acc[i][jj][rr];
}

// ---------------------------------------------------------------------------
// k_mlp: one block per batch row b (320 threads):
//   slab-reduce -> bias/relu/BN1 -> h1 (LDS); hetmat row;
//   W2 GEMV -> relu/BN2 -> h2 (LDS); mu/ls GEMVs; softmax -> theta; kld partial
// ---------------------------------------------------------------------------
__global__ __launch_bounds__(320) void k_mlp(
    const float* __restrict__ part, int S,
    const float* __restrict__ b1,
    const float* __restrict__ g1, const float* __restrict__ bb1,
    const float* __restrict__ m1, const float* __restrict__ v1,
    const float* __restrict__ W2, const float* __restrict__ b2,
    const float* __restrict__ g2, const float* __restrict__ bb2,
    const float* __restrict__ m2, const float* __restrict__ v2,
    const float* __restrict__ muW, const float* __restrict__ mub,
    const float* __restrict__ lsW, const float* __restrict__ lsb,
    short* __restrict__ thetab, float* __restrict__ thetaf,
    float* __restrict__ hetmat, float* __restrict__ kldp)
{
  __shared__ __attribute__((aligned(16))) float h1s[H_];
  __shared__ __attribute__((aligned(16))) float h2s[H_];
  const int b = blockIdx.x;
  const int tid = threadIdx.x;
  const float* pb = part + (size_t)b * NW;

  if (tid < H_) {
    float s0 = 0.f, s1 = 0.f, s2 = 0.f, s3 = 0.f;
    int i = 0;
    for (; i + 4 <= S; i += 4) {
      s0 += pb[(size_t)(i + 0) * (B_ * NW) + tid];
      s1 += pb[(size_t)(i + 1) * (B_ * NW) + tid];
      s2 += pb[(size_t)(i + 2) * (B_ * NW) + tid];
      s3 += pb[(size_t)(i + 3) * (B_ * NW) + tid];
    }
    for (; i < S; ++i) s0 += pb[(size_t)i * (B_ * NW) + tid];
    float s = (s0 + s1) + (s2 + s3);
    float x = fmaxf(s + b1[tid], 0.f);
    h1s[tid] = (x - m1[tid]) * rsqrtf(v1[tid] + 1e-5f) * g1[tid] + bb1[tid];
  }
  if (tid < 51) {
    float s0 = 0.f, s1 = 0.f;
    int i = 0;
    for (; i + 2 <= S; i += 2) {
      s0 += pb[(size_t)(i + 0) * (B_ * NW) + 320 + tid];
      s1 += pb[(size_t)(i + 1) * (B_ * NW) + 320 + tid];
    }
    for (; i < S; ++i) s0 += pb[(size_t)i * (B_ * NW) + 320 + tid];
    hetmat[(size_t)b * KP + tid] = s0 + s1;
  }
  __syncthreads();
  if (tid < H_) {
    const float4* wr = (const float4*)(W2 + (size_t)tid * H_);
    const float4* hr = (const float4*)h1s;
    float acc = 0.f;
    for (int q = 0; q < H_ / 4; ++q) {
      float4 w = wr[q], h = hr[q];
      acc += w.x * h.x + w.y * h.y + w.z * h.z + w.w * h.w;
    }
    float x = fmaxf(acc + b2[tid], 0.f);
    h2s[tid] = (x - m2[tid]) * rsqrtf(v2[tid] + 1e-5f) * g2[tid] + bb2[tid];
  }
  __syncthreads();
  if (tid < 64) {
    float mu = 0.f, ls = 0.f;
    if (tid < K_) {
      const float4* mr = (const float4*)(muW + (size_t)tid * H_);
      const float4* lr = (const float4*)(lsW + (size_t)tid * H_);
      const float4* hr = (const float4*)h2s;
      for (int q = 0; q < H_ / 4; ++q) {
        float4 h = hr[q], a = mr[q], c = lr[q];
        mu += a.x * h.x + a.y * h.y + a.z * h.z + a.w * h.w;
        ls += c.x * h.x + c.y * h.y + c.z * h.z + c.w * h.w;
      }
      mu += mub[tid]; ls += lsb[tid];
    }
    float term = (tid < K_) ? (1.f + ls - mu * mu - __expf(ls)) : 0.f;
    float ts = term;
    #pragma unroll
    for (int off = 1; off < 64; off <<= 1) ts += __shfl_xor(ts, off, 64);
    if (tid == 0) kldp[b] = ts;
    float mv = (tid < K_) ? mu : -INFINITY;
    #pragma unroll
    for (int off = 1; off < 64; off <<= 1) mv = fmaxf(mv, __shfl_xor(mv, off, 64));
    float e = (tid < K_) ? __expf(mu - mv) : 0.f;
    float se = e;
    #pragma unroll
    for (int off = 1; off < 64; off <<= 1) se += __shfl_xor(se, off, 64);
    float tv = (tid < K_) ? (e / se) : 0.f;
    thetaf[(size_t)b * KP + tid] = tv;
    thetab[(size_t)b * KP + tid] = bf16s(tv);
  }
}

// ---------------------------------------------------------------------------
// k_c1: c1p[vs][b] = partial sum_v exp(theta[b].beta[v] + br[v])
// ---------------------------------------------------------------------------
__global__ __launch_bounds__(256, 2) void k_c1(
    const short* __restrict__ thetab, const short* __restrict__ betab,
    const float* __restrict__ br, float* __restrict__ c1p)
{
  const int blk = blockIdx.x;
  const int bm = blk & 7, vs = blk >> 3;
  const int lane = threadIdx.x & 63, wv = threadIdx.x >> 6;
  const int l15 = lane & 15, quad = lane >> 4;
  const int b0 = bm * 64 + wv * 16;
  const short8* arow = (const short8*)(thetab + (size_t)(b0 + l15) * KP);
  const short8 a0 = arow[quad], a1 = arow[4 + quad];
  int t0 = vs * 33, t1 = t0 + 33; if (t1 > 3125) t1 = 3125;
  float p0 = 0.f, p1 = 0.f, p2 = 0.f, p3 = 0.f;
  auto body = [&](int tt) {
    const int v0 = tt * 16;
    const short8* brow = (const short8*)(betab + (size_t)(v0 + l15) * KP);
    short8 q0 = brow[quad], q1 = brow[4 + quad];
    f32x4 acc = {0.f, 0.f, 0.f, 0.f};
    acc = __builtin_amdgcn_mfma_f32_16x16x32_bf16(a0, q0, acc, 0, 0, 0);
    acc = __builtin_amdgcn_mfma_f32_16x16x32_bf16(a1, q1, acc, 0, 0, 0);
    const float brv = br[v0 + l15];
    p0 += __expf(acc[0] + brv);
    p1 += __expf(acc[1] + brv);
    p2 += __expf(acc[2] + brv);
    p3 += __expf(acc[3] + brv);
  };
  int tt = t0;
  for (; tt + 2 <= t1; tt += 2) { body(tt); body(tt + 1); }
  if (tt < t1) body(tt);
  #pragma unroll
  for (int off = 1; off < 16; off <<= 1) {
    p0 += __shfl_xor(p0, off, 16);
    p1 += __shfl_xor(p1, off, 16);
    p2 += __shfl_xor(p2, off, 16);
    p3 += __shfl_xor(p3, off, 16);
  }
  if (l15 == 0) {
    float* dst = c1p + (size_t)vs * B_ + b0 + quad * 4;
    dst[0] = p0; dst[1] = p1; dst[2] = p2; dst[3] = p3;
  }
}

// ---------------------------------------------------------------------------
// k_d1: lse; expected_pred + mse; reduce partial arrays; out[1], out[2]
// ---------------------------------------------------------------------------
static __device__ __forceinline__ float blockred512(float x, float* red) {
  #pragma unroll
  for (int off = 1; off < 64; off <<= 1) x += __shfl_xor(x, off, 64);
  if ((threadIdx.x & 63) == 0) red[threadIdx.x >> 6] = x;
  __syncthreads();
  float r = 0.f;
  if (threadIdx.x == 0)
    for (int i = 0; i < 8; ++i) r += red[i];
  __syncthreads();
  return r;
}

__global__ __launch_bounds__(512) void k_d1(
    const float* __restrict__ c1p, const float* __restrict__ kldp,
    const float* __restrict__ pg, const float* __restrict__ pbr,
    const float* __restrict__ pbw2,
    const float* __restrict__ hetmat, const float* __restrict__ thetaf,
    const float* __restrict__ labels, const float* __restrict__ topic_w,
    const float* __restrict__ topic_b, const float* __restrict__ bow_b,
    float* __restrict__ lseb, float* __restrict__ out)
{
  __shared__ float red[8];
  const int b = threadIdx.x;
  float se = 0.f;
  for (int i = 0; i < 96; ++i) se += c1p[(size_t)i * B_ + b];
  lseb[b] = __logf(se);
  float het = 0.f, tpc = 0.f;
  #pragma unroll
  for (int k = 0; k < K_; ++k) {
    float th = thetaf[(size_t)b * KP + k];
    het += th * hetmat[(size_t)b * KP + k];
    tpc += th * topic_w[k];
  }
  float ep = het + hetmat[(size_t)b * KP + 50] + bow_b[0] + tpc + topic_b[0];
  float d = ep - labels[b];
  float mse  = blockred512(d * d, red);
  float kl   = blockred512(kldp[b], red);
  float sg = 0.f, sr = 0.f, sw = 0.f;
  for (int i = b; i < NSB; i += 512) { sg += pg[i]; sr += pbr[i]; sw += pbw2[i]; }
  sg = blockred512(sg, red);
  sr = blockred512(sr, red);
  sw = blockred512(sw, red);
  if (b == 0) {
    out[1] = 0.0005f * sr + mse / (float)B_ + 5e-6f * sg + 0.0005f * sqrtf(sw);
    out[2] = -0.5f * kl / (float)B_;
  }
}

// ---------------------------------------------------------------------------
// k_c2: c2p[blk] = partial of sum_bv log(exp(logit-lse)+1e-6)*bows
// ---------------------------------------------------------------------------
__global__ __launch_bounds__(256, 2) void k_c2(
    const short* __restrict__ thetab, const short* __restrict__ betab,
    const float* __restrict__ br, const float* __restrict__ lseb,
    const float* __restrict__ bows, float* __restrict__ c2p)
{
  __shared__ float red[4];
  const int blk = blockIdx.x;
  const int bm = blk & 7, vs = blk >> 3;
  const int lane = threadIdx.x & 63, wv = threadIdx.x >> 6;
  const int l15 = lane & 15, quad = lane >> 4;
  const int b0 = bm * 64 + wv * 16;
  const short8* arow = (const short8*)(thetab + (size_t)(b0 + l15) * KP);
  const short8 a0 = arow[quad], a1 = arow[4 + quad];
  float lse4[4]; const float* bro[4];
  #pragma unroll
  for (int rr = 0; rr < 4; ++rr) {
    lse4[rr] = lseb[b0 + quad * 4 + rr];
    bro[rr] = bows + (size_t)(b0 + quad * 4 + rr) * V_;
  }
  int t0 = vs * 33, t1 = t0 + 33; if (t1 > 3125) t1 = 3125;
  float p = 0.f;
  auto body = [&](int tt) {
    const int v0 = tt * 16;
    const int v = v0 + l15;
    const short8* brow = (const short8*)(betab + (size_t)v * KP);
    short8 q0 = brow[quad], q1 = brow[4 + quad];
    f32x4 acc = {0.f, 0.f, 0.f, 0.f};
    acc = __builtin_amdgcn_mfma_f32_16x16x32_bf16(a0, q0, acc, 0, 0, 0);
    acc = __builtin_amdgcn_mfma_f32_16x16x32_bf16(a1, q1, acc, 0, 0, 0);
    const float brv = br[v];
    #pragma unroll
    for (int rr = 0; rr < 4; ++rr) {
      float l = acc[rr] + brv - lse4[rr];
      float pr = __logf(__expf(l) + 1e-6f);
      p += pr * bro[rr][v];
    }
  };
  int tt = t0;
  for (; tt + 2 <= t1; tt += 2) { body(tt); body(tt + 1); }
  if (tt < t1) body(tt);
  #pragma unroll
  for (int off = 1; off < 64; off <<= 1) p += __shfl_xor(p, off, 64);
  if (lane == 0) red[wv] = p;
  __syncthreads();
  if (threadIdx.x == 0) c2p[blk] = red[0] + red[1] + red[2] + red[3];
}

// k_d2: out[0] = -sum(c2p)/B
__global__ __launch_bounds__(256) void k_d2(
    const float* __restrict__ c2p, float* __restrict__ out)
{
  __shared__ float red[4];
  float s = 0.f;
  for (int i = threadIdx.x; i < 768; i += 256) s += c2p[i];
  #pragma unroll
  for (int off = 1; off < 64; off <<= 1) s += __shfl_xor(s, off, 64);
  if ((threadIdx.x & 63) == 0) red[threadIdx.x >> 6] = s;
  __syncthreads();
  if (threadIdx.x == 0)
    out[0] = -(red[0] + red[1] + red[2] + red[3]) / (float)B_;
}

// ---------------------------------------------------------------------------
extern "C" void kernel_launch(void* const* d_in, const int* in_sizes, int n_in,
                              void* d_out, int out_size, void* d_ws, size_t ws_size,
                              hipStream_t stream)
{
  const float* bows    = (const float*)d_in[0];
  const float* nb      = (const float*)d_in[1];
  const float* labels  = (const float*)d_in[2];
  const float* W1      = (const float*)d_in[3];
  const float* b1      = (const float*)d_in[4];
  const float* W2      = (const float*)d_in[5];
  const float* b2      = (const float*)d_in[6];
  const float* bn1_g   = (const float*)d_in[7];
  const float* bn1_b   = (const float*)d_in[8];
  const float* bn1_m   = (const float*)d_in[9];
  const float* bn1_v   = (const float*)d_in[10];
  const float* bn2_g   = (const float*)d_in[11];
  const float* bn2_b   = (const float*)d_in[12];
  const float* bn2_m   = (const float*)d_in[13];
  const float* bn2_v   = (const float*)d_in[14];
  const float* muW     = (const float*)d_in[15];
  const float* mub     = (const float*)d_in[16];
  const float* lsW     = (const float*)d_in[17];
  const float* lsb     = (const float*)d_in[18];
  const float* beta    = (const float*)d_in[19];
  const float* gamma   = (const float*)d_in[20];
  const float* brates  = (const float*)d_in[21];
  const float* bow_w   = (const float*)d_in[22];
  const float* bow_b   = (const float*)d_in[23];
  const float* topic_w = (const float*)d_in[24];
  const float* topic_b = (const float*)d_in[25];
  float* out = (float*)d_out;

  char* ws = (char*)d_ws;
  size_t off = 0;
  auto take = [&](size_t bytes) { void* p = ws + off; off = (off + bytes + 255) & ~(size_t)255; return p; };

  short* Wcatb   = (short*)take((size_t)NSTEP * 12288 * 2);  // 38.4 MB
  short* nbb     = (short*)take((size_t)NSTEP * 16384 * 2);  // 51.2 MB
  short* betab   = (short*)take((size_t)V_ * 64 * 2);        // 6.4 MB
  short* thetab  = (short*)take((size_t)B_ * KP * 2);
  float* thetaf  = (float*)take((size_t)B_ * KP * 4);
  float* hetmat  = (float*)take((size_t)B_ * KP * 4);
  float* kldp    = (float*)take((size_t)B_ * 4);
  float* c1p     = (float*)take((size_t)96 * B_ * 4);
  float* c2p     = (float*)take((size_t)768 * 4);
  float* lse_    = (float*)take((size_t)B_ * 4);
  float* pg      = (float*)take((size_t)NSB * 4);
  float* pbr     = (float*)take((size_t)NSB * 4);
  float* pbw2    = (float*)take((size_t)NSB * 4);
  float* part1   = (float*)(ws + off);
  size_t remain = (ws_size > off) ? (ws_size - off) : 0;
  int S = (int)(remain / ((size_t)B_ * NW * 4));
  if (S > 64) S = 64;
  if (S < 1)  S = 1;
  const int sps = (NSTEP + S - 1) / S;

  k_prep<<<NB1C + NSB + NB2C, 256, 0, stream>>>(
      W1, beta, gamma, brates, bow_w, nb, Wcatb, betab, nbb, pg, pbr, pbw2);
  k_bg  <<<12 * S, 256, 0, stream>>>(nbb, Wcatb, part1, sps);
  k_mlp <<<B_, 320, 0, stream>>>(part1, S, b1, bn1_g, bn1_b, bn1_m, bn1_v,
                                 W2, b2, bn2_g, bn2_b, bn2_m, bn2_v,
                                 muW, mub, lsW, lsb, thetab, thetaf, hetmat, kldp);
  k_c1  <<<8 * 96, 256, 0, stream>>>(thetab, betab, brates, c1p);
  k_d1  <<<1, 512, 0, stream>>>(c1p, kldp, pg, pbr, pbw2, hetmat, thetaf,
                                labels, topic_w, topic_b, bow_b, lse_, out);
  k_c2  <<<8 * 96, 256, 0, stream>>>(thetab, betab, brates, lse_, bows, c2p);
  k_d2  <<<1, 256, 0, stream>>>(c2p, out);
}

// Round 2
// 478.497 us; speedup vs baseline: 1.0066x; 1.0066x over previous
//
#include <hip/hip_runtime.h>
#include <hip/hip_bf16.h>
#include <math.h>

// ---------------------------------------------------------------------------
// HeterogeneousSupervisedTopicModel fwd: recon_loss, other_loss, kld_theta
// B=512, V=50000, K=50, H=300.
// Round 6: k_prep convert phases as LDS-staged tile transposes.
// Prior rounds proved 2.25 TB/s is an access-pattern wall (identical BW under
// two launch structures): 128B-granularity scattered reads at 200KB row
// stride. New structure: 64-row x 8-st tiles; reads 1KB-contiguous per row,
// writes 4KB-contiguous per st via LDS. Layouts byte-identical downstream.
//   nbb  [st][512][32] bf16   (nb converted, zero-padded to VP)
//   Wcatb[st][384][32] bf16   (rows 0..299 W1, 320..369 beta*gamma, 370 bow_w)
// ---------------------------------------------------------------------------

#define B_  512
#define V_  50000
#define VP  50016    // V padded to multiple of 32
#define K_  50
#define H_  300
#define KP  64
#define NW  384
#define NSTEP 1563   // VP/32
#define NSB  782     // ceil(V/64)  beta/gamma blocks
#define TS   8       // sts per transpose tile (256 cols)
#define NT_ST 196    // ceil(NSTEP/TS)
#define NB_W1T (5*NT_ST)   // 980  W1 tiles (5 row-bands of 64/44)
#define NB_NBT (8*NT_ST)   // 1568 nb tiles (8 row-bands of 64)

typedef __attribute__((ext_vector_type(8))) short short8;
typedef __attribute__((ext_vector_type(4))) float f32x4;

static __device__ __forceinline__ short bf16s(float f) {
  unsigned int u = __builtin_bit_cast(unsigned int, f);
  u += 0x7fffu + ((u >> 16) & 1u);
  return (short)(u >> 16);
}

static __device__ __forceinline__ unsigned int pkbf(float lo, float hi) {
  __hip_bfloat162 t = __float22bfloat162_rn(float2{lo, hi});
  unsigned int u; __builtin_memcpy(&u, &t, 4); return u;
}

// ---------------------------------------------------------------------------
// k_prep, three block ranges in one launch:
//  [0, NB_W1T)            : Wcatb rows 0..299 = bf16(W1), via LDS tile transpose
//  [NB_W1T, +NSB)         : per 64-v tile: Wcatb rows 300..383 (320..369 =
//                           (beta*gamma)^T, 370 = bow_w, rest 0); betab[V][64];
//                           partials pg/pbr/pbw2
//  [NB_W1T+NSB, +NB_NBT)  : nbb = bf16(nb), via LDS tile transpose
// ---------------------------------------------------------------------------
__global__ __launch_bounds__(256) void k_prep(
    const float* __restrict__ W1,
    const float* __restrict__ beta, const float* __restrict__ gamma,
    const float* __restrict__ br,   const float* __restrict__ bw,
    const float* __restrict__ nb,
    short* __restrict__ Wcatb, short* __restrict__ betab,
    short* __restrict__ nbb,
    float* __restrict__ pg, float* __restrict__ pbr, float* __restrict__ pbw2)
{
  __shared__ __attribute__((aligned(16))) short lds[16384];   // 32 KB
  const int tid = threadIdx.x;

  if (blockIdx.x < NB_W1T || blockIdx.x >= NB_W1T + NSB) {
    // ---- tile transpose-convert: src f32 row-major -> dst bf16 K-tile-major
    const float* src; short* dst; int r0, nrows, frame, blk;
    if (blockIdx.x < NB_W1T) {
      blk = blockIdx.x; src = W1; dst = Wcatb; frame = 12288;
      const int band = blk / NT_ST;
      r0 = band * 64; nrows = (band == 4) ? 44 : 64;
    } else {
      blk = blockIdx.x - (NB_W1T + NSB); src = nb; dst = nbb; frame = 16384;
      const int band = blk / NT_ST;
      r0 = band * 64; nrows = 64;
    }
    const int stile = blk % NT_ST;
    const int s0 = stile * TS;
    int ns = NSTEP - s0; if (ns > TS) ns = TS;

    const int row = tid >> 2, p = tid & 3;
    if (row < nrows) {
      const float4* rp = (const float4*)(src + (size_t)(r0 + row) * V_) + (size_t)s0 * 8;
      const int c4lim = 12500 - s0 * 8;   // valid float4s within tile cols
      auto doj = [&](int j) {
        const int f4 = p + 4 * j;
        float4 v = {0.f, 0.f, 0.f, 0.f};
        if (f4 < c4lim) v = rp[f4];
        unsigned int u0 = pkbf(v.x, v.y), u1 = pkbf(v.z, v.w);
        unsigned long long uu = ((unsigned long long)u1 << 32) | (unsigned long long)u0;
        *(unsigned long long*)((char*)lds + ((f4 >> 3) * 4096 + row * 64 + (f4 & 7) * 8)) = uu;
      };
      if (ns == TS) {
        #pragma unroll
        for (int jj = 0; jj < 8; ++jj) doj(jj);
        #pragma unroll
        for (int jj = 8; jj < 16; ++jj) doj(jj);
      } else {
        for (int j = 0; j < 2 * ns; ++j) doj(j);
      }
    }
    __syncthreads();
    // write out: per st, nrows*32 shorts contiguous (4 KB when nrows=64)
    for (int stl = 0; stl < ns; ++stl) {
      short* db = dst + (size_t)(s0 + stl) * frame + r0 * 32;
      const short8* sb = (const short8*)((char*)lds + stl * 4096);
      for (int w = tid; w < nrows * 4; w += 256)
        *(short8*)(db + w * 8) = sb[w];
    }
    return;
  }

  // ---- beta/gamma tile ----
  short* sbt = lds;                 // [64*52]
  short* bbt = lds + 64 * 52;      // [64*52]
  float* redA = (float*)(lds + 8192);  // 4 floats, byte 16384 (16B aligned)

  const int blk = blockIdx.x - NB_W1T;               // 0..781
  const int v0 = blk * 64;
  const int nvalid = (V_ - v0 < 64) ? (V_ - v0) : 64;
  const int nwrite = (VP - v0 < 64) ? (VP - v0) : 64;

  const int nf4 = (nvalid * 50) / 4;
  const float4* bsrc = (const float4*)(beta  + (size_t)v0 * 50);
  const float4* gsrc = (const float4*)(gamma + (size_t)v0 * 50);
  float gabs = 0.f;
  for (int f = tid; f < nf4; f += 256) {
    float4 bv = bsrc[f];
    float4 gv = gsrc[f];
    float be[4] = {bv.x, bv.y, bv.z, bv.w};
    float ge[4] = {gv.x, gv.y, gv.z, gv.w};
    #pragma unroll
    for (int e = 0; e < 4; ++e) {
      int idx = f * 4 + e;
      int j = idx / 50, k = idx - j * 50;
      gabs += fabsf(ge[e]);
      bbt[j * 52 + k] = bf16s(be[e]);
      sbt[j * 52 + k] = bf16s(be[e] * ge[e]);
    }
  }
  #pragma unroll
  for (int off = 1; off < 64; off <<= 1) gabs += __shfl_xor(gabs, off, 64);
  if ((tid & 63) == 0) redA[tid >> 6] = gabs;
  if (tid < 64) {
    float s1 = 0.f, s2 = 0.f;
    if (tid < nvalid) {
      s1 = fabsf(br[v0 + tid]);
      float w = bw[v0 + tid]; s2 = w * w;
    }
    #pragma unroll
    for (int off = 1; off < 64; off <<= 1) {
      s1 += __shfl_xor(s1, off, 64);
      s2 += __shfl_xor(s2, off, 64);
    }
    if (tid == 0) { pbr[blk] = s1; pbw2[blk] = s2; }
  }
  __syncthreads();
  if (tid == 0) pg[blk] = redA[0] + redA[1] + redA[2] + redA[3];

  const int j = tid & 63;
  const int q = tid >> 6;
  // Wcatb rows 300..383, this tile's 2 st-chunks (st = blk*2 + j/32)
  #pragma unroll
  for (int p = 0; p < 21; ++p) {
    const int kk = p * 4 + q;          // 0..83
    if (j < nwrite) {
      short val = 0;
      if (j < nvalid) {
        if (kk >= 20 && kk < 70)      val = sbt[j * 52 + (kk - 20)];
        else if (kk == 70)            val = bf16s(bw[v0 + j]);
      }
      Wcatb[(size_t)(blk * 2 + (j >> 5)) * 12288 + (300 + kk) * 32 + (j & 31)] = val;
    }
  }
  // betab rows
  if (j < nvalid) {
    __attribute__((aligned(16))) short tmp[16];
    #pragma unroll
    for (int t = 0; t < 16; ++t) {
      int k = q * 16 + t;
      tmp[t] = (k < K_) ? bbt[j * 52 + k] : (short)0;
    }
    short8* dst = (short8*)(betab + (size_t)(v0 + j) * 64 + q * 16);
    dst[0] = *(const short8*)&tmp[0];
    dst[1] = *(const short8*)&tmp[8];
  }
}

// ---------------------------------------------------------------------------
// k_bg: part[s][512][384] = slab-partial of nbb @ Wcatb^T (both bf16,
// K-tile-major).  Inner loop: 8 contiguous 16B loads + 16 MFMA, no cvt.
// Register double-buffer.  grid = 12 * S, 3 blocks/CU.
// ---------------------------------------------------------------------------
__global__ __launch_bounds__(256, 3) void k_bg(
    const short* __restrict__ Ab, const short* __restrict__ Bb,
    float* __restrict__ part, int sps)
{
  const int t = blockIdx.x;
  const int s = t / 12;
  const int r = t % 12;
  const int bni = r % 3, bmi = r / 3;
  const int lane = threadIdx.x & 63, wv = threadIdx.x >> 6;
  const int l15 = lane & 15, quad = lane >> 4;
  const int m0 = bmi * 128 + (wv & 1) * 64;
  const int n0 = bni * 128 + (wv >> 1) * 64;
  int st0 = s * sps, st1 = st0 + sps;
  if (st0 > NSTEP) st0 = NSTEP;
  if (st1 > NSTEP) st1 = NSTEP;
  const int nst = st1 - st0;

  const short8* pa = (const short8*)Ab + (size_t)st0 * 2048 + (m0 + l15) * 4 + quad;
  const short8* pb = (const short8*)Bb + (size_t)st0 * 1536 + (n0 + l15) * 4 + quad;

  f32x4 acc[4][4];
  #pragma unroll
  for (int i = 0; i < 4; ++i)
    #pragma unroll
    for (int jj = 0; jj < 4; ++jj) acc[i][jj] = f32x4{0.f, 0.f, 0.f, 0.f};

  short8 A0[4], A1[4], B0[4], B1[4];

  auto ld = [&](short8 (&Af)[4], short8 (&Bf)[4]) {
    #pragma unroll
    for (int i = 0; i < 4; ++i) Af[i] = pa[i * 64];
    #pragma unroll
    for (int jj = 0; jj < 4; ++jj) Bf[jj] = pb[jj * 64];
    pa += 2048; pb += 1536;
  };
  auto comp = [&](short8 (&Af)[4], short8 (&Bf)[4]) {
    #pragma unroll
    for (int i = 0; i < 4; ++i)
      #pragma unroll
      for (int jj = 0; jj < 4; ++jj)
        acc[i][jj] = __builtin_amdgcn_mfma_f32_16x16x32_bf16(Af[i], Bf[jj], acc[i][jj], 0, 0, 0);
  };

  if (nst > 0) {
    ld(A0, B0);
    int k = 0;
    for (; k + 2 <= nst; k += 2) {
      ld(A1, B1);                      // step k+1 (valid: k+1 < nst)
      comp(A0, B0);                    // step k
      if (k + 2 < nst) ld(A0, B0);     // step k+2
      comp(A1, B1);                    // step k+1
    }
    if (k < nst) comp(A0, B0);         // odd tail
  }

  float* op = part + (size_t)s * (B_ * NW);
  #pragma unroll
  for (int i = 0; i < 4; ++i)
    #pragma unroll
    for (int jj = 0; jj < 4; ++jj)
      #pragma unroll
      for (int rr = 0; rr < 4; ++rr)
        op[(size_t)(m0 + 16 * i + quad * 4 + rr) * NW + (n0 + 16 * jj + l15)] = acc[i][jj][rr];
}

// ---------------------------------------------------------------------------
// k_mlp: one block per batch row b (320 threads):
//   slab-reduce -> bias/relu/BN1 -> h1 (LDS); hetmat row;
//   W2 GEMV -> relu/BN2 -> h2 (LDS); mu/ls GEMVs; softmax -> theta; kld partial
// ---------------------------------------------------------------------------
__global__ __launch_bounds__(320) void k_mlp(
    const float* __restrict__ part, int S,
    const float* __restrict__ b1,
    const float* __restrict__ g1, const float* __restrict__ bb1,
    const float* __restrict__ m1, const float* __restrict__ v1,
    const float* __restrict__ W2, const float* __restrict__ b2,
    const float* __restrict__ g2, const float* __restrict__ bb2,
    const float* __restrict__ m2, const float* __restrict__ v2,
    const float* __restrict__ muW, const float* __restrict__ mub,
    const float* __restrict__ lsW, const float* __restrict__ lsb,
    short* __restrict__ thetab, float* __restrict__ thetaf,
    float* __restrict__ hetmat, float* __restrict__ kldp)
{
  __shared__ __attribute__((aligned(16))) float h1s[H_];
  __shared__ __attribute__((aligned(16))) float h2s[H_];
  const int b = blockIdx.x;
  const int tid = threadIdx.x;
  const float* pb = part + (size_t)b * NW;

  if (tid < H_) {
    float s0 = 0.f, s1 = 0.f, s2 = 0.f, s3 = 0.f;
    int i = 0;
    for (; i + 4 <= S; i += 4) {
      s0 += pb[(size_t)(i + 0) * (B_ * NW) + tid];
      s1 += pb[(size_t)(i + 1) * (B_ * NW) + tid];
      s2 += pb[(size_t)(i + 2) * (B_ * NW) + tid];
      s3 += pb[(size_t)(i + 3) * (B_ * NW) + tid];
    }
    for (; i < S; ++i) s0 += pb[(size_t)i * (B_ * NW) + tid];
    float s = (s0 + s1) + (s2 + s3);
    float x = fmaxf(s + b1[tid], 0.f);
    h1s[tid] = (x - m1[tid]) * rsqrtf(v1[tid] + 1e-5f) * g1[tid] + bb1[tid];
  }
  if (tid < 51) {
    float s0 = 0.f, s1 = 0.f;
    int i = 0;
    for (; i + 2 <= S; i += 2) {
      s0 += pb[(size_t)(i + 0) * (B_ * NW) + 320 + tid];
      s1 += pb[(size_t)(i + 1) * (B_ * NW) + 320 + tid];
    }
    for (; i < S; ++i) s0 += pb[(size_t)i * (B_ * NW) + 320 + tid];
    hetmat[(size_t)b * KP + tid] = s0 + s1;
  }
  __syncthreads();
  if (tid < H_) {
    const float4* wr = (const float4*)(W2 + (size_t)tid * H_);
    const float4* hr = (const float4*)h1s;
    float acc = 0.f;
    for (int q = 0; q < H_ / 4; ++q) {
      float4 w = wr[q], h = hr[q];
      acc += w.x * h.x + w.y * h.y + w.z * h.z + w.w * h.w;
    }
    float x = fmaxf(acc + b2[tid], 0.f);
    h2s[tid] = (x - m2[tid]) * rsqrtf(v2[tid] + 1e-5f) * g2[tid] + bb2[tid];
  }
  __syncthreads();
  if (tid < 64) {
    float mu = 0.f, ls = 0.f;
    if (tid < K_) {
      const float4* mr = (const float4*)(muW + (size_t)tid * H_);
      const float4* lr = (const float4*)(lsW + (size_t)tid * H_);
      const float4* hr = (const float4*)h2s;
      for (int q = 0; q < H_ / 4; ++q) {
        float4 h = hr[q], a = mr[q], c = lr[q];
        mu += a.x * h.x + a.y * h.y + a.z * h.z + a.w * h.w;
        ls += c.x * h.x + c.y * h.y + c.z * h.z + c.w * h.w;
      }
      mu += mub[tid]; ls += lsb[tid];
    }
    float term = (tid < K_) ? (1.f + ls - mu * mu - __expf(ls)) : 0.f;
    float ts = term;
    #pragma unroll
    for (int off = 1; off < 64; off <<= 1) ts += __shfl_xor(ts, off, 64);
    if (tid == 0) kldp[b] = ts;
    float mv = (tid < K_) ? mu : -INFINITY;
    #pragma unroll
    for (int off = 1; off < 64; off <<= 1) mv = fmaxf(mv, __shfl_xor(mv, off, 64));
    float e = (tid < K_) ? __expf(mu - mv) : 0.f;
    float se = e;
    #pragma unroll
    for (int off = 1; off < 64; off <<= 1) se += __shfl_xor(se, off, 64);
    float tv = (tid < K_) ? (e / se) : 0.f;
    thetaf[(size_t)b * KP + tid] = tv;
    thetab[(size_t)b * KP + tid] = bf16s(tv);
  }
}

// ---------------------------------------------------------------------------
// k_c1: c1p[vs][b] = partial sum_v exp(theta[b].beta[v] + br[v])
// ---------------------------------------------------------------------------
__global__ __launch_bounds__(256, 2) void k_c1(
    const short* __restrict__ thetab, const short* __restrict__ betab,
    const float* __restrict__ br, float* __restrict__ c1p)
{
  const int blk = blockIdx.x;
  const int bm = blk & 7, vs = blk >> 3;
  const int lane = threadIdx.x & 63, wv = threadIdx.x >> 6;
  const int l15 = lane & 15, quad = lane >> 4;
  const int b0 = bm * 64 + wv * 16;
  const short8* arow = (const short8*)(thetab + (size_t)(b0 + l15) * KP);
  const short8 a0 = arow[quad], a1 = arow[4 + quad];
  int t0 = vs * 33, t1 = t0 + 33; if (t1 > 3125) t1 = 3125;
  float p0 = 0.f, p1 = 0.f, p2 = 0.f, p3 = 0.f;
  auto body = [&](int tt) {
    const int v0 = tt * 16;
    const short8* brow = (const short8*)(betab + (size_t)(v0 + l15) * KP);
    short8 q0 = brow[quad], q1 = brow[4 + quad];
    f32x4 acc = {0.f, 0.f, 0.f, 0.f};
    acc = __builtin_amdgcn_mfma_f32_16x16x32_bf16(a0, q0, acc, 0, 0, 0);
    acc = __builtin_amdgcn_mfma_f32_16x16x32_bf16(a1, q1, acc, 0, 0, 0);
    const float brv = br[v0 + l15];
    p0 += __expf(acc[0] + brv);
    p1 += __expf(acc[1] + brv);
    p2 += __expf(acc[2] + brv);
    p3 += __expf(acc[3] + brv);
  };
  int tt = t0;
  for (; tt + 2 <= t1; tt += 2) { body(tt); body(tt + 1); }
  if (tt < t1) body(tt);
  #pragma unroll
  for (int off = 1; off < 16; off <<= 1) {
    p0 += __shfl_xor(p0, off, 16);
    p1 += __shfl_xor(p1, off, 16);
    p2 += __shfl_xor(p2, off, 16);
    p3 += __shfl_xor(p3, off, 16);
  }
  if (l15 == 0) {
    float* dst = c1p + (size_t)vs * B_ + b0 + quad * 4;
    dst[0] = p0; dst[1] = p1; dst[2] = p2; dst[3] = p3;
  }
}

// ---------------------------------------------------------------------------
// k_d1: lse; expected_pred + mse; reduce partial arrays; out[1], out[2]
// ---------------------------------------------------------------------------
static __device__ __forceinline__ float blockred512(float x, float* red) {
  #pragma unroll
  for (int off = 1; off < 64; off <<= 1) x += __shfl_xor(x, off, 64);
  if ((threadIdx.x & 63) == 0) red[threadIdx.x >> 6] = x;
  __syncthreads();
  float r = 0.f;
  if (threadIdx.x == 0)
    for (int i = 0; i < 8; ++i) r += red[i];
  __syncthreads();
  return r;
}

__global__ __launch_bounds__(512) void k_d1(
    const float* __restrict__ c1p, const float* __restrict__ kldp,
    const float* __restrict__ pg, const float* __restrict__ pbr,
    const float* __restrict__ pbw2,
    const float* __restrict__ hetmat, const float* __restrict__ thetaf,
    const float* __restrict__ labels, const float* __restrict__ topic_w,
    const float* __restrict__ topic_b, const float* __restrict__ bow_b,
    float* __restrict__ lseb, float* __restrict__ out)
{
  __shared__ float red[8];
  const int b = threadIdx.x;
  float se = 0.f;
  for (int i = 0; i < 96; ++i) se += c1p[(size_t)i * B_ + b];
  lseb[b] = __logf(se);
  float het = 0.f, tpc = 0.f;
  #pragma unroll
  for (int k = 0; k < K_; ++k) {
    float th = thetaf[(size_t)b * KP + k];
    het += th * hetmat[(size_t)b * KP + k];
    tpc += th * topic_w[k];
  }
  float ep = het + hetmat[(size_t)b * KP + 50] + bow_b[0] + tpc + topic_b[0];
  float d = ep - labels[b];
  float mse  = blockred512(d * d, red);
  float kl   = blockred512(kldp[b], red);
  float sg = 0.f, sr = 0.f, sw = 0.f;
  for (int i = b; i < NSB; i += 512) { sg += pg[i]; sr += pbr[i]; sw += pbw2[i]; }
  sg = blockred512(sg, red);
  sr = blockred512(sr, red);
  sw = blockred512(sw, red);
  if (b == 0) {
    out[1] = 0.0005f * sr + mse / (float)B_ + 5e-6f * sg + 0.0005f * sqrtf(sw);
    out[2] = -0.5f * kl / (float)B_;
  }
}

// ---------------------------------------------------------------------------
// k_c2: c2p[blk] = partial of sum_bv log(exp(logit-lse)+1e-6)*bows
// ---------------------------------------------------------------------------
__global__ __launch_bounds__(256, 2) void k_c2(
    const short* __restrict__ thetab, const short* __restrict__ betab,
    const float* __restrict__ br, const float* __restrict__ lseb,
    const float* __restrict__ bows, float* __restrict__ c2p)
{
  __shared__ float red[4];
  const int blk = blockIdx.x;
  const int bm = blk & 7, vs = blk >> 3;
  const int lane = threadIdx.x & 63, wv = threadIdx.x >> 6;
  const int l15 = lane & 15, quad = lane >> 4;
  const int b0 = bm * 64 + wv * 16;
  const short8* arow = (const short8*)(thetab + (size_t)(b0 + l15) * KP);
  const short8 a0 = arow[quad], a1 = arow[4 + quad];
  float lse4[4]; const float* bro[4];
  #pragma unroll
  for (int rr = 0; rr < 4; ++rr) {
    lse4[rr] = lseb[b0 + quad * 4 + rr];
    bro[rr] = bows + (size_t)(b0 + quad * 4 + rr) * V_;
  }
  int t0 = vs * 33, t1 = t0 + 33; if (t1 > 3125) t1 = 3125;
  float p = 0.f;
  auto body = [&](int tt) {
    const int v0 = tt * 16;
    const int v = v0 + l15;
    const short8* brow = (const short8*)(betab + (size_t)v * KP);
    short8 q0 = brow[quad], q1 = brow[4 + quad];
    f32x4 acc = {0.f, 0.f, 0.f, 0.f};
    acc = __builtin_amdgcn_mfma_f32_16x16x32_bf16(a0, q0, acc, 0, 0, 0);
    acc = __builtin_amdgcn_mfma_f32_16x16x32_bf16(a1, q1, acc, 0, 0, 0);
    const float brv = br[v];
    #pragma unroll
    for (int rr = 0; rr < 4; ++rr) {
      float l = acc[rr] + brv - lse4[rr];
      float pr = __logf(__expf(l) + 1e-6f);
      p += pr * bro[rr][v];
    }
  };
  int tt = t0;
  for (; tt + 2 <= t1; tt += 2) { body(tt); body(tt + 1); }
  if (tt < t1) body(tt);
  #pragma unroll
  for (int off = 1; off < 64; off <<= 1) p += __shfl_xor(p, off, 64);
  if (lane == 0) red[wv] = p;
  __syncthreads();
  if (threadIdx.x == 0) c2p[blk] = red[0] + red[1] + red[2] + red[3];
}

// k_d2: out[0] = -sum(c2p)/B
__global__ __launch_bounds__(256) void k_d2(
    const float* __restrict__ c2p, float* __restrict__ out)
{
  __shared__ float red[4];
  float s = 0.f;
  for (int i = threadIdx.x; i < 768; i += 256) s += c2p[i];
  #pragma unroll
  for (int off = 1; off < 64; off <<= 1) s += __shfl_xor(s, off, 64);
  if ((threadIdx.x & 63) == 0) red[threadIdx.x >> 6] = s;
  __syncthreads();
  if (threadIdx.x == 0)
    out[0] = -(red[0] + red[1] + red[2] + red[3]) / (float)B_;
}

// ---------------------------------------------------------------------------
extern "C" void kernel_launch(void* const* d_in, const int* in_sizes, int n_in,
                              void* d_out, int out_size, void* d_ws, size_t ws_size,
                              hipStream_t stream)
{
  const float* bows    = (const float*)d_in[0];
  const float* nb      = (const float*)d_in[1];
  const float* labels  = (const float*)d_in[2];
  const float* W1      = (const float*)d_in[3];
  const float* b1      = (const float*)d_in[4];
  const float* W2      = (const float*)d_in[5];
  const float* b2      = (const float*)d_in[6];
  const float* bn1_g   = (const float*)d_in[7];
  const float* bn1_b   = (const float*)d_in[8];
  const float* bn1_m   = (const float*)d_in[9];
  const float* bn1_v   = (const float*)d_in[10];
  const float* bn2_g   = (const float*)d_in[11];
  const float* bn2_b   = (const float*)d_in[12];
  const float* bn2_m   = (const float*)d_in[13];
  const float* bn2_v   = (const float*)d_in[14];
  const float* muW     = (const float*)d_in[15];
  const float* mub     = (const float*)d_in[16];
  const float* lsW     = (const float*)d_in[17];
  const float* lsb     = (const float*)d_in[18];
  const float* beta    = (const float*)d_in[19];
  const float* gamma   = (const float*)d_in[20];
  const float* brates  = (const float*)d_in[21];
  const float* bow_w   = (const float*)d_in[22];
  const float* bow_b   = (const float*)d_in[23];
  const float* topic_w = (const float*)d_in[24];
  const float* topic_b = (const float*)d_in[25];
  float* out = (float*)d_out;

  char* ws = (char*)d_ws;
  size_t off = 0;
  auto take = [&](size_t bytes) { void* p = ws + off; off = (off + bytes + 255) & ~(size_t)255; return p; };

  short* Wcatb   = (short*)take((size_t)NSTEP * 12288 * 2);  // 38.4 MB
  short* nbb     = (short*)take((size_t)NSTEP * 16384 * 2);  // 51.2 MB
  short* betab   = (short*)take((size_t)V_ * 64 * 2);        // 6.4 MB
  short* thetab  = (short*)take((size_t)B_ * KP * 2);
  float* thetaf  = (float*)take((size_t)B_ * KP * 4);
  float* hetmat  = (float*)take((size_t)B_ * KP * 4);
  float* kldp    = (float*)take((size_t)B_ * 4);
  float* c1p     = (float*)take((size_t)96 * B_ * 4);
  float* c2p     = (float*)take((size_t)768 * 4);
  float* lse_    = (float*)take((size_t)B_ * 4);
  float* pg      = (float*)take((size_t)NSB * 4);
  float* pbr     = (float*)take((size_t)NSB * 4);
  float* pbw2    = (float*)take((size_t)NSB * 4);
  float* part1   = (float*)(ws + off);
  size_t remain = (ws_size > off) ? (ws_size - off) : 0;
  int S = (int)(remain / ((size_t)B_ * NW * 4));
  if (S > 64) S = 64;
  if (S < 1)  S = 1;
  const int sps = (NSTEP + S - 1) / S;

  k_prep<<<NB_W1T + NSB + NB_NBT, 256, 0, stream>>>(
      W1, beta, gamma, brates, bow_w, nb, Wcatb, betab, nbb, pg, pbr, pbw2);
  k_bg  <<<12 * S, 256, 0, stream>>>(nbb, Wcatb, part1, sps);
  k_mlp <<<B_, 320, 0, stream>>>(part1, S, b1, bn1_g, bn1_b, bn1_m, bn1_v,
                                 W2, b2, bn2_g, bn2_b, bn2_m, bn2_v,
                                 muW, mub, lsW, lsb, thetab, thetaf, hetmat, kldp);
  k_c1  <<<8 * 96, 256, 0, stream>>>(thetab, betab, brates, c1p);
  k_d1  <<<1, 512, 0, stream>>>(c1p, kldp, pg, pbr, pbw2, hetmat, thetaf,
                                labels, topic_w, topic_b, bow_b, lse_, out);
  k_c2  <<<8 * 96, 256, 0, stream>>>(thetab, betab, brates, lse_, bows, c2p);
  k_d2  <<<1, 256, 0, stream>>>(c2p, out);
}

// Round 3
// 476.027 us; speedup vs baseline: 1.0118x; 1.0052x over previous
//
#include <hip/hip_runtime.h>
#include <hip/hip_bf16.h>
#include <math.h>

// ---------------------------------------------------------------------------
// HeterogeneousSupervisedTopicModel fwd: recon_loss, other_loss, kld_theta
// B=512, V=50000, K=50, H=300.
// Round 7: k_prep transpose reads = 1KB-contiguous-per-instruction bursts via
// async global_load_lds (wave-linear dest). Theory: prior 2.1 TB/s wall was
// DRAM page thrash from 16-scattered-64B-per-instr loads; FETCH_SIZE was
// already minimal (r2), so only burst length can move BW.
//   nbb  [st][512][32] bf16   (nb converted, zero-padded to VP)
//   Wcatb[st][384][32] bf16   (rows 0..299 W1, 320..369 beta*gamma, 370 bow_w)
// ---------------------------------------------------------------------------

#define B_  512
#define V_  50000
#define VP  50016    // V padded to multiple of 32
#define K_  50
#define H_  300
#define KP  64
#define NW  384
#define NSTEP 1563   // VP/32
#define NSB  782     // ceil(V/64)  beta/gamma blocks
#define TS   8       // sts per transpose tile (256 f32 cols = 1KB rows)
#define NT_ST 196    // ceil(NSTEP/TS)
#define NB_W1T (5*NT_ST)   // 980  W1 tiles (5 row-bands of 64/44)
#define NB_NBT (8*NT_ST)   // 1568 nb tiles (8 row-bands of 64)
#define LROW 264     // LDS row stride in f32 (264*4 = 1056 B, breaks conflicts)

typedef __attribute__((ext_vector_type(8))) short short8;
typedef __attribute__((ext_vector_type(4))) float f32x4;

typedef __attribute__((address_space(3))) void lds_void;
typedef __attribute__((address_space(1))) const void gbl_void;

static __device__ __forceinline__ void gl_lds16(const void* g, void* l) {
  __builtin_amdgcn_global_load_lds((gbl_void*)g, (lds_void*)l, 16, 0, 0);
}

static __device__ __forceinline__ short bf16s(float f) {
  unsigned int u = __builtin_bit_cast(unsigned int, f);
  u += 0x7fffu + ((u >> 16) & 1u);
  return (short)(u >> 16);
}

static __device__ __forceinline__ unsigned int pkbf(float lo, float hi) {
  __hip_bfloat162 t = __float22bfloat162_rn(float2{lo, hi});
  unsigned int u; __builtin_memcpy(&u, &t, 4); return u;
}

static __device__ __forceinline__ short8 to_bf8(float4 a, float4 b) {
  unsigned int u[4];
  u[0] = pkbf(a.x, a.y); u[1] = pkbf(a.z, a.w);
  u[2] = pkbf(b.x, b.y); u[3] = pkbf(b.z, b.w);
  short8 r; __builtin_memcpy(&r, u, 16); return r;
}

// ---------------------------------------------------------------------------
// k_prep, three block ranges in one launch:
//  [0, NB_W1T)            : Wcatb rows 0..299 = bf16(W1), async 1KB-burst tiles
//  [NB_W1T, +NSB)         : per 64-v tile: Wcatb rows 300..383 (320..369 =
//                           (beta*gamma)^T, 370 = bow_w, rest 0); betab[V][64];
//                           partials pg/pbr/pbw2
//  [NB_W1T+NSB, +NB_NBT)  : nbb = bf16(nb), async 1KB-burst tiles
// ---------------------------------------------------------------------------
__global__ __launch_bounds__(256) void k_prep(
    const float* __restrict__ W1,
    const float* __restrict__ beta, const float* __restrict__ gamma,
    const float* __restrict__ br,   const float* __restrict__ bw,
    const float* __restrict__ nb,
    short* __restrict__ Wcatb, short* __restrict__ betab,
    short* __restrict__ nbb,
    float* __restrict__ pg, float* __restrict__ pbr, float* __restrict__ pbw2)
{
  __shared__ __attribute__((aligned(16))) char smem[64 * LROW * 4];  // 67.6 KB
  const int tid = threadIdx.x;
  const short8 z8 = {0, 0, 0, 0, 0, 0, 0, 0};

  if (blockIdx.x < NB_W1T || blockIdx.x >= NB_W1T + NSB) {
    // ---- tile transpose-convert: src f32 row-major -> dst bf16 K-tile-major
    const float* src; short* dst; int r0, nrows, frame, blk;
    if (blockIdx.x < NB_W1T) {
      blk = blockIdx.x; src = W1; dst = Wcatb; frame = 12288;
      const int band = blk / NT_ST;
      r0 = band * 64; nrows = (band == 4) ? 44 : 64;
    } else {
      blk = blockIdx.x - (NB_W1T + NSB); src = nb; dst = nbb; frame = 16384;
      const int band = blk / NT_ST;
      r0 = band * 64; nrows = 64;
    }
    const int stile = blk % NT_ST;
    const int s0 = stile * TS;
    int ns = NSTEP - s0; if (ns > TS) ns = TS;

    float* ldsf = (float*)smem;
    const int wv = tid >> 6, lane = tid & 63;
    // load phase: wave wv stages rows wv*16+j; each instr = 1KB contiguous
    int col = s0 * 32 + lane * 4;
    if (col > V_ - 4) col = V_ - 4;            // clamp pad lanes (never read)
    #pragma unroll
    for (int j = 0; j < 16; ++j) {
      const int row = wv * 16 + j;             // wave-uniform
      if (row < nrows)
        gl_lds16(src + (size_t)(r0 + row) * V_ + col, ldsf + row * LROW);
    }
    asm volatile("s_waitcnt vmcnt(0)" ::: "memory");
    __syncthreads();
    // cvt + store: per st, 64 rows x 32 shorts contiguous (1KB/wave-instr)
    const int row = tid >> 2, qo = tid & 3;
    if (row < nrows) {
      const float* lp = ldsf + row * LROW + qo * 8;
      short* dp = dst + (size_t)s0 * frame + (size_t)(r0 + row) * 32 + qo * 8;
      for (int stl = 0; stl < ns; ++stl) {
        const int kb = (s0 + stl) * 32 + qo * 8;
        short8 o = z8;
        if (kb + 8 <= V_) {
          const float* p = lp + stl * 32;
          o = to_bf8(*(const float4*)p, *(const float4*)(p + 4));
        }
        *(short8*)(dp + (size_t)stl * frame) = o;
      }
    }
    return;
  }

  // ---- beta/gamma tile ----
  short* sbt = (short*)smem;                   // [64*52]
  short* bbt = sbt + 64 * 52;                  // [64*52]
  float* redA = (float*)(smem + 13312);        // 4 floats (16B aligned)

  const int blk = blockIdx.x - NB_W1T;         // 0..781
  const int v0 = blk * 64;
  const int nvalid = (V_ - v0 < 64) ? (V_ - v0) : 64;
  const int nwrite = (VP - v0 < 64) ? (VP - v0) : 64;

  const int nf4 = (nvalid * 50) / 4;
  const float4* bsrc = (const float4*)(beta  + (size_t)v0 * 50);
  const float4* gsrc = (const float4*)(gamma + (size_t)v0 * 50);
  float gabs = 0.f;
  for (int f = tid; f < nf4; f += 256) {
    float4 bv = bsrc[f];
    float4 gv = gsrc[f];
    float be[4] = {bv.x, bv.y, bv.z, bv.w};
    float ge[4] = {gv.x, gv.y, gv.z, gv.w};
    #pragma unroll
    for (int e = 0; e < 4; ++e) {
      int idx = f * 4 + e;
      int j = idx / 50, k = idx - j * 50;
      gabs += fabsf(ge[e]);
      bbt[j * 52 + k] = bf16s(be[e]);
      sbt[j * 52 + k] = bf16s(be[e] * ge[e]);
    }
  }
  #pragma unroll
  for (int off = 1; off < 64; off <<= 1) gabs += __shfl_xor(gabs, off, 64);
  if ((tid & 63) == 0) redA[tid >> 6] = gabs;
  if (tid < 64) {
    float s1 = 0.f, s2 = 0.f;
    if (tid < nvalid) {
      s1 = fabsf(br[v0 + tid]);
      float w = bw[v0 + tid]; s2 = w * w;
    }
    #pragma unroll
    for (int off = 1; off < 64; off <<= 1) {
      s1 += __shfl_xor(s1, off, 64);
      s2 += __shfl_xor(s2, off, 64);
    }
    if (tid == 0) { pbr[blk] = s1; pbw2[blk] = s2; }
  }
  __syncthreads();
  if (tid == 0) pg[blk] = redA[0] + redA[1] + redA[2] + redA[3];

  const int j = tid & 63;
  const int q = tid >> 6;
  // Wcatb rows 300..383, this tile's 2 st-chunks (st = blk*2 + j/32)
  #pragma unroll
  for (int p = 0; p < 21; ++p) {
    const int kk = p * 4 + q;          // 0..83
    if (j < nwrite) {
      short val = 0;
      if (j < nvalid) {
        if (kk >= 20 && kk < 70)      val = sbt[j * 52 + (kk - 20)];
        else if (kk == 70)            val = bf16s(bw[v0 + j]);
      }
      Wcatb[(size_t)(blk * 2 + (j >> 5)) * 12288 + (300 + kk) * 32 + (j & 31)] = val;
    }
  }
  // betab rows
  if (j < nvalid) {
    __attribute__((aligned(16))) short tmp[16];
    #pragma unroll
    for (int t = 0; t < 16; ++t) {
      int k = q * 16 + t;
      tmp[t] = (k < K_) ? bbt[j * 52 + k] : (short)0;
    }
    short8* dst = (short8*)(betab + (size_t)(v0 + j) * 64 + q * 16);
    dst[0] = *(const short8*)&tmp[0];
    dst[1] = *(const short8*)&tmp[8];
  }
}

// ---------------------------------------------------------------------------
// k_bg: part[s][512][384] = slab-partial of nbb @ Wcatb^T (both bf16,
// K-tile-major).  Inner loop: 8 contiguous 16B loads + 16 MFMA, no cvt.
// Register double-buffer.  grid = 12 * S, 3 blocks/CU.
// ---------------------------------------------------------------------------
__global__ __launch_bounds__(256, 3) void k_bg(
    const short* __restrict__ Ab, const short* __restrict__ Bb,
    float* __restrict__ part, int sps)
{
  const int t = blockIdx.x;
  const int s = t / 12;
  const int r = t % 12;
  const int bni = r % 3, bmi = r / 3;
  const int lane = threadIdx.x & 63, wv = threadIdx.x >> 6;
  const int l15 = lane & 15, quad = lane >> 4;
  const int m0 = bmi * 128 + (wv & 1) * 64;
  const int n0 = bni * 128 + (wv >> 1) * 64;
  int st0 = s * sps, st1 = st0 + sps;
  if (st0 > NSTEP) st0 = NSTEP;
  if (st1 > NSTEP) st1 = NSTEP;
  const int nst = st1 - st0;

  const short8* pa = (const short8*)Ab + (size_t)st0 * 2048 + (m0 + l15) * 4 + quad;
  const short8* pb = (const short8*)Bb + (size_t)st0 * 1536 + (n0 + l15) * 4 + quad;

  f32x4 acc[4][4];
  #pragma unroll
  for (int i = 0; i < 4; ++i)
    #pragma unroll
    for (int jj = 0; jj < 4; ++jj) acc[i][jj] = f32x4{0.f, 0.f, 0.f, 0.f};

  short8 A0[4], A1[4], B0[4], B1[4];

  auto ld = [&](short8 (&Af)[4], short8 (&Bf)[4]) {
    #pragma unroll
    for (int i = 0; i < 4; ++i) Af[i] = pa[i * 64];
    #pragma unroll
    for (int jj = 0; jj < 4; ++jj) Bf[jj] = pb[jj * 64];
    pa += 2048; pb += 1536;
  };
  auto comp = [&](short8 (&Af)[4], short8 (&Bf)[4]) {
    #pragma unroll
    for (int i = 0; i < 4; ++i)
      #pragma unroll
      for (int jj = 0; jj < 4; ++jj)
        acc[i][jj] = __builtin_amdgcn_mfma_f32_16x16x32_bf16(Af[i], Bf[jj], acc[i][jj], 0, 0, 0);
  };

  if (nst > 0) {
    ld(A0, B0);
    int k = 0;
    for (; k + 2 <= nst; k += 2) {
      ld(A1, B1);                      // step k+1 (valid: k+1 < nst)
      comp(A0, B0);                    // step k
      if (k + 2 < nst) ld(A0, B0);     // step k+2
      comp(A1, B1);                    // step k+1
    }
    if (k < nst) comp(A0, B0);         // odd tail
  }

  float* op = part + (size_t)s * (B_ * NW);
  #pragma unroll
  for (int i = 0; i < 4; ++i)
    #pragma unroll
    for (int jj = 0; jj < 4; ++jj)
      #pragma unroll
      for (int rr = 0; rr < 4; ++rr)
        op[(size_t)(m0 + 16 * i + quad * 4 + rr) * NW + (n0 + 16 * jj + l15)] = acc[i][jj][rr];
}

// ---------------------------------------------------------------------------
// k_mlp: one block per batch row b (320 threads):
//   slab-reduce -> bias/relu/BN1 -> h1 (LDS); hetmat row;
//   W2 GEMV -> relu/BN2 -> h2 (LDS); mu/ls GEMVs; softmax -> theta; kld partial
// ---------------------------------------------------------------------------
__global__ __launch_bounds__(320) void k_mlp(
    const float* __restrict__ part, int S,
    const float* __restrict__ b1,
    const float* __restrict__ g1, const float* __restrict__ bb1,
    const float* __restrict__ m1, const float* __restrict__ v1,
    const float* __restrict__ W2, const float* __restrict__ b2,
    const float* __restrict__ g2, const float* __restrict__ bb2,
    const float* __restrict__ m2, const float* __restrict__ v2,
    const float* __restrict__ muW, const float* __restrict__ mub,
    const float* __restrict__ lsW, const float* __restrict__ lsb,
    short* __restrict__ thetab, float* __restrict__ thetaf,
    float* __restrict__ hetmat, float* __restrict__ kldp)
{
  __shared__ __attribute__((aligned(16))) float h1s[H_];
  __shared__ __attribute__((aligned(16))) float h2s[H_];
  const int b = blockIdx.x;
  const int tid = threadIdx.x;
  const float* pb = part + (size_t)b * NW;

  if (tid < H_) {
    float s0 = 0.f, s1 = 0.f, s2 = 0.f, s3 = 0.f;
    int i = 0;
    for (; i + 4 <= S; i += 4) {
      s0 += pb[(size_t)(i + 0) * (B_ * NW) + tid];
      s1 += pb[(size_t)(i + 1) * (B_ * NW) + tid];
      s2 += pb[(size_t)(i + 2) * (B_ * NW) + tid];
      s3 += pb[(size_t)(i + 3) * (B_ * NW) + tid];
    }
    for (; i < S; ++i) s0 += pb[(size_t)i * (B_ * NW) + tid];
    float s = (s0 + s1) + (s2 + s3);
    float x = fmaxf(s + b1[tid], 0.f);
    h1s[tid] = (x - m1[tid]) * rsqrtf(v1[tid] + 1e-5f) * g1[tid] + bb1[tid];
  }
  if (tid < 51) {
    float s0 = 0.f, s1 = 0.f;
    int i = 0;
    for (; i + 2 <= S; i += 2) {
      s0 += pb[(size_t)(i + 0) * (B_ * NW) + 320 + tid];
      s1 += pb[(size_t)(i + 1) * (B_ * NW) + 320 + tid];
    }
    for (; i < S; ++i) s0 += pb[(size_t)i * (B_ * NW) + 320 + tid];
    hetmat[(size_t)b * KP + tid] = s0 + s1;
  }
  __syncthreads();
  if (tid < H_) {
    const float4* wr = (const float4*)(W2 + (size_t)tid * H_);
    const float4* hr = (const float4*)h1s;
    float acc = 0.f;
    for (int q = 0; q < H_ / 4; ++q) {
      float4 w = wr[q], h = hr[q];
      acc += w.x * h.x + w.y * h.y + w.z * h.z + w.w * h.w;
    }
    float x = fmaxf(acc + b2[tid], 0.f);
    h2s[tid] = (x - m2[tid]) * rsqrtf(v2[tid] + 1e-5f) * g2[tid] + bb2[tid];
  }
  __syncthreads();
  if (tid < 64) {
    float mu = 0.f, ls = 0.f;
    if (tid < K_) {
      const float4* mr = (const float4*)(muW + (size_t)tid * H_);
      const float4* lr = (const float4*)(lsW + (size_t)tid * H_);
      const float4* hr = (const float4*)h2s;
      for (int q = 0; q < H_ / 4; ++q) {
        float4 h = hr[q], a = mr[q], c = lr[q];
        mu += a.x * h.x + a.y * h.y + a.z * h.z + a.w * h.w;
        ls += c.x * h.x + c.y * h.y + c.z * h.z + c.w * h.w;
      }
      mu += mub[tid]; ls += lsb[tid];
    }
    float term = (tid < K_) ? (1.f + ls - mu * mu - __expf(ls)) : 0.f;
    float ts = term;
    #pragma unroll
    for (int off = 1; off < 64; off <<= 1) ts += __shfl_xor(ts, off, 64);
    if (tid == 0) kldp[b] = ts;
    float mv = (tid < K_) ? mu : -INFINITY;
    #pragma unroll
    for (int off = 1; off < 64; off <<= 1) mv = fmaxf(mv, __shfl_xor(mv, off, 64));
    float e = (tid < K_) ? __expf(mu - mv) : 0.f;
    float se = e;
    #pragma unroll
    for (int off = 1; off < 64; off <<= 1) se += __shfl_xor(se, off, 64);
    float tv = (tid < K_) ? (e / se) : 0.f;
    thetaf[(size_t)b * KP + tid] = tv;
    thetab[(size_t)b * KP + tid] = bf16s(tv);
  }
}

// ---------------------------------------------------------------------------
// k_c1: c1p[vs][b] = partial sum_v exp(theta[b].beta[v] + br[v])
// ---------------------------------------------------------------------------
__global__ __launch_bounds__(256, 2) void k_c1(
    const short* __restrict__ thetab, const short* __restrict__ betab,
    const float* __restrict__ br, float* __restrict__ c1p)
{
  const int blk = blockIdx.x;
  const int bm = blk & 7, vs = blk >> 3;
  const int lane = threadIdx.x & 63, wv = threadIdx.x >> 6;
  const int l15 = lane & 15, quad = lane >> 4;
  const int b0 = bm * 64 + wv * 16;
  const short8* arow = (const short8*)(thetab + (size_t)(b0 + l15) * KP);
  const short8 a0 = arow[quad], a1 = arow[4 + quad];
  int t0 = vs * 33, t1 = t0 + 33; if (t1 > 3125) t1 = 3125;
  float p0 = 0.f, p1 = 0.f, p2 = 0.f, p3 = 0.f;
  auto body = [&](int tt) {
    const int v0 = tt * 16;
    const short8* brow = (const short8*)(betab + (size_t)(v0 + l15) * KP);
    short8 q0 = brow[quad], q1 = brow[4 + quad];
    f32x4 acc = {0.f, 0.f, 0.f, 0.f};
    acc = __builtin_amdgcn_mfma_f32_16x16x32_bf16(a0, q0, acc, 0, 0, 0);
    acc = __builtin_amdgcn_mfma_f32_16x16x32_bf16(a1, q1, acc, 0, 0, 0);
    const float brv = br[v0 + l15];
    p0 += __expf(acc[0] + brv);
    p1 += __expf(acc[1] + brv);
    p2 += __expf(acc[2] + brv);
    p3 += __expf(acc[3] + brv);
  };
  int tt = t0;
  for (; tt + 2 <= t1; tt += 2) { body(tt); body(tt + 1); }
  if (tt < t1) body(tt);
  #pragma unroll
  for (int off = 1; off < 16; off <<= 1) {
    p0 += __shfl_xor(p0, off, 16);
    p1 += __shfl_xor(p1, off, 16);
    p2 += __shfl_xor(p2, off, 16);
    p3 += __shfl_xor(p3, off, 16);
  }
  if (l15 == 0) {
    float* dst = c1p + (size_t)vs * B_ + b0 + quad * 4;
    dst[0] = p0; dst[1] = p1; dst[2] = p2; dst[3] = p3;
  }
}

// ---------------------------------------------------------------------------
// k_d1: lse; expected_pred + mse; reduce partial arrays; out[1], out[2]
// ---------------------------------------------------------------------------
static __device__ __forceinline__ float blockred512(float x, float* red) {
  #pragma unroll
  for (int off = 1; off < 64; off <<= 1) x += __shfl_xor(x, off, 64);
  if ((threadIdx.x & 63) == 0) red[threadIdx.x >> 6] = x;
  __syncthreads();
  float r = 0.f;
  if (threadIdx.x == 0)
    for (int i = 0; i < 8; ++i) r += red[i];
  __syncthreads();
  return r;
}

__global__ __launch_bounds__(512) void k_d1(
    const float* __restrict__ c1p, const float* __restrict__ kldp,
    const float* __restrict__ pg, const float* __restrict__ pbr,
    const float* __restrict__ pbw2,
    const float* __restrict__ hetmat, const float* __restrict__ thetaf,
    const float* __restrict__ labels, const float* __restrict__ topic_w,
    const float* __restrict__ topic_b, const float* __restrict__ bow_b,
    float* __restrict__ lseb, float* __restrict__ out)
{
  __shared__ float red[8];
  const int b = threadIdx.x;
  float se = 0.f;
  for (int i = 0; i < 96; ++i) se += c1p[(size_t)i * B_ + b];
  lseb[b] = __logf(se);
  float het = 0.f, tpc = 0.f;
  #pragma unroll
  for (int k = 0; k < K_; ++k) {
    float th = thetaf[(size_t)b * KP + k];
    het += th * hetmat[(size_t)b * KP + k];
    tpc += th * topic_w[k];
  }
  float ep = het + hetmat[(size_t)b * KP + 50] + bow_b[0] + tpc + topic_b[0];
  float d = ep - labels[b];
  float mse  = blockred512(d * d, red);
  float kl   = blockred512(kldp[b], red);
  float sg = 0.f, sr = 0.f, sw = 0.f;
  for (int i = b; i < NSB; i += 512) { sg += pg[i]; sr += pbr[i]; sw += pbw2[i]; }
  sg = blockred512(sg, red);
  sr = blockred512(sr, red);
  sw = blockred512(sw, red);
  if (b == 0) {
    out[1] = 0.0005f * sr + mse / (float)B_ + 5e-6f * sg + 0.0005f * sqrtf(sw);
    out[2] = -0.5f * kl / (float)B_;
  }
}

// ---------------------------------------------------------------------------
// k_c2: c2p[blk] = partial of sum_bv log(exp(logit-lse)+1e-6)*bows
// ---------------------------------------------------------------------------
__global__ __launch_bounds__(256, 2) void k_c2(
    const short* __restrict__ thetab, const short* __restrict__ betab,
    const float* __restrict__ br, const float* __restrict__ lseb,
    const float* __restrict__ bows, float* __restrict__ c2p)
{
  __shared__ float red[4];
  const int blk = blockIdx.x;
  const int bm = blk & 7, vs = blk >> 3;
  const int lane = threadIdx.x & 63, wv = threadIdx.x >> 6;
  const int l15 = lane & 15, quad = lane >> 4;
  const int b0 = bm * 64 + wv * 16;
  const short8* arow = (const short8*)(thetab + (size_t)(b0 + l15) * KP);
  const short8 a0 = arow[quad], a1 = arow[4 + quad];
  float lse4[4]; const float* bro[4];
  #pragma unroll
  for (int rr = 0; rr < 4; ++rr) {
    lse4[rr] = lseb[b0 + quad * 4 + rr];
    bro[rr] = bows + (size_t)(b0 + quad * 4 + rr) * V_;
  }
  int t0 = vs * 33, t1 = t0 + 33; if (t1 > 3125) t1 = 3125;
  float p = 0.f;
  auto body = [&](int tt) {
    const int v0 = tt * 16;
    const int v = v0 + l15;
    const short8* brow = (const short8*)(betab + (size_t)v * KP);
    short8 q0 = brow[quad], q1 = brow[4 + quad];
    f32x4 acc = {0.f, 0.f, 0.f, 0.f};
    acc = __builtin_amdgcn_mfma_f32_16x16x32_bf16(a0, q0, acc, 0, 0, 0);
    acc = __builtin_amdgcn_mfma_f32_16x16x32_bf16(a1, q1, acc, 0, 0, 0);
    const float brv = br[v];
    #pragma unroll
    for (int rr = 0; rr < 4; ++rr) {
      float l = acc[rr] + brv - lse4[rr];
      float pr = __logf(__expf(l) + 1e-6f);
      p += pr * bro[rr][v];
    }
  };
  int tt = t0;
  for (; tt + 2 <= t1; tt += 2) { body(tt); body(tt + 1); }
  if (tt < t1) body(tt);
  #pragma unroll
  for (int off = 1; off < 64; off <<= 1) p += __shfl_xor(p, off, 64);
  if (lane == 0) red[wv] = p;
  __syncthreads();
  if (threadIdx.x == 0) c2p[blk] = red[0] + red[1] + red[2] + red[3];
}

// k_d2: out[0] = -sum(c2p)/B
__global__ __launch_bounds__(256) void k_d2(
    const float* __restrict__ c2p, float* __restrict__ out)
{
  __shared__ float red[4];
  float s = 0.f;
  for (int i = threadIdx.x; i < 768; i += 256) s += c2p[i];
  #pragma unroll
  for (int off = 1; off < 64; off <<= 1) s += __shfl_xor(s, off, 64);
  if ((threadIdx.x & 63) == 0) red[threadIdx.x >> 6] = s;
  __syncthreads();
  if (threadIdx.x == 0)
    out[0] = -(red[0] + red[1] + red[2] + red[3]) / (float)B_;
}

// ---------------------------------------------------------------------------
extern "C" void kernel_launch(void* const* d_in, const int* in_sizes, int n_in,
                              void* d_out, int out_size, void* d_ws, size_t ws_size,
                              hipStream_t stream)
{
  const float* bows    = (const float*)d_in[0];
  const float* nb      = (const float*)d_in[1];
  const float* labels  = (const float*)d_in[2];
  const float* W1      = (const float*)d_in[3];
  const float* b1      = (const float*)d_in[4];
  const float* W2      = (const float*)d_in[5];
  const float* b2      = (const float*)d_in[6];
  const float* bn1_g   = (const float*)d_in[7];
  const float* bn1_b   = (const float*)d_in[8];
  const float* bn1_m   = (const float*)d_in[9];
  const float* bn1_v   = (const float*)d_in[10];
  const float* bn2_g   = (const float*)d_in[11];
  const float* bn2_b   = (const float*)d_in[12];
  const float* bn2_m   = (const float*)d_in[13];
  const float* bn2_v   = (const float*)d_in[14];
  const float* muW     = (const float*)d_in[15];
  const float* mub     = (const float*)d_in[16];
  const float* lsW     = (const float*)d_in[17];
  const float* lsb     = (const float*)d_in[18];
  const float* beta    = (const float*)d_in[19];
  const float* gamma   = (const float*)d_in[20];
  const float* brates  = (const float*)d_in[21];
  const float* bow_w   = (const float*)d_in[22];
  const float* bow_b   = (const float*)d_in[23];
  const float* topic_w = (const float*)d_in[24];
  const float* topic_b = (const float*)d_in[25];
  float* out = (float*)d_out;

  char* ws = (char*)d_ws;
  size_t off = 0;
  auto take = [&](size_t bytes) { void* p = ws + off; off = (off + bytes + 255) & ~(size_t)255; return p; };

  short* Wcatb   = (short*)take((size_t)NSTEP * 12288 * 2);  // 38.4 MB
  short* nbb     = (short*)take((size_t)NSTEP * 16384 * 2);  // 51.2 MB
  short* betab   = (short*)take((size_t)V_ * 64 * 2);        // 6.4 MB
  short* thetab  = (short*)take((size_t)B_ * KP * 2);
  float* thetaf  = (float*)take((size_t)B_ * KP * 4);
  float* hetmat  = (float*)take((size_t)B_ * KP * 4);
  float* kldp    = (float*)take((size_t)B_ * 4);
  float* c1p     = (float*)take((size_t)96 * B_ * 4);
  float* c2p     = (float*)take((size_t)768 * 4);
  float* lse_    = (float*)take((size_t)B_ * 4);
  float* pg      = (float*)take((size_t)NSB * 4);
  float* pbr     = (float*)take((size_t)NSB * 4);
  float* pbw2    = (float*)take((size_t)NSB * 4);
  float* part1   = (float*)(ws + off);
  size_t remain = (ws_size > off) ? (ws_size - off) : 0;
  int S = (int)(remain / ((size_t)B_ * NW * 4));
  if (S > 64) S = 64;
  if (S < 1)  S = 1;
  const int sps = (NSTEP + S - 1) / S;

  k_prep<<<NB_W1T + NSB + NB_NBT, 256, 0, stream>>>(
      W1, beta, gamma, brates, bow_w, nb, Wcatb, betab, nbb, pg, pbr, pbw2);
  k_bg  <<<12 * S, 256, 0, stream>>>(nbb, Wcatb, part1, sps);
  k_mlp <<<B_, 320, 0, stream>>>(part1, S, b1, bn1_g, bn1_b, bn1_m, bn1_v,
                                 W2, b2, bn2_g, bn2_b, bn2_m, bn2_v,
                                 muW, mub, lsW, lsb, thetab, thetaf, hetmat, kldp);
  k_c1  <<<8 * 96, 256, 0, stream>>>(thetab, betab, brates, c1p);
  k_d1  <<<1, 512, 0, stream>>>(c1p, kldp, pg, pbr, pbw2, hetmat, thetaf,
                                labels, topic_w, topic_b, bow_b, lse_, out);
  k_c2  <<<8 * 96, 256, 0, stream>>>(thetab, betab, brates, lse_, bows, c2p);
  k_d2  <<<1, 256, 0, stream>>>(c2p, out);
}